// Round 2
// baseline (2043.374 us; speedup 1.0000x reference)
//
#include <hip/hip_runtime.h>
#include <hip/hip_cooperative_groups.h>
#include <math.h>

namespace cg = cooperative_groups;

// Problem constants
#define BB 64
#define LL 24
#define DD 512
#define GG 2560        // 5*H
#define NSTEP 23       // LL-1
#define KS 4           // k-chunks in per-step a/b GEMM (phase B)
#define GRID_LOOP 256  // cooperative grid size
#define NTASK 320      // 80 n-tiles (NT=64) x KS k-chunks

__device__ __forceinline__ float sigm(float x) { return 1.0f / (1.0f + __expf(-x)); }

// ---------------------------------------------------------------------------
// Big fp32 GEMM, conflict-free microtile. C[m][n] = sum_k A[m][k]*W[n][k] (+bias)
// 128x128 tile, KT=16, K=512 fixed. Thread microtile: 8m x (4n + 4n@+64).
// MODE 0 = WORD (W row-major 1024x512, bias, out h|c split at n=512)
// MODE 1 = AB0  (W = comp_W halves: n<2560 -> row n cols[0:512]; else row n-2560 cols[512:1024])
// LDS stride 132 floats: 16B-aligned rows; B reads stride-4 -> 2-way (free);
// A reads are 16-lane broadcasts at banks {0,8,16,24} (free).
// ---------------------------------------------------------------------------
template <int MODE>
__global__ __launch_bounds__(256) void gemm_big(const float* __restrict__ A,
                                                const float* __restrict__ Wt,
                                                const float* __restrict__ bias,
                                                float* __restrict__ O0,
                                                float* __restrict__ O1) {
    __shared__ float As[16][132];
    __shared__ float Bs[16][132];
    const int tid = threadIdx.x;
    const int n0 = blockIdx.x * 128;
    const int m0 = blockIdx.y * 128;
    const int tn = tid & 15;
    const int tm = tid >> 4;

    float acc[8][8];
#pragma unroll
    for (int y = 0; y < 8; ++y)
#pragma unroll
        for (int x = 0; x < 8; ++x) acc[y][x] = 0.f;

    for (int kt = 0; kt < 512; kt += 16) {
        // A tile: 128 rows x 16 k  (512 float4 loads, 2 per thread)
#pragma unroll
        for (int ii = 0; ii < 2; ++ii) {
            int idx = tid + ii * 256;
            int r = idx >> 2, c4 = idx & 3;
            float4 v = *(const float4*)(A + (size_t)(m0 + r) * DD + kt + c4 * 4);
            As[c4 * 4 + 0][r] = v.x;
            As[c4 * 4 + 1][r] = v.y;
            As[c4 * 4 + 2][r] = v.z;
            As[c4 * 4 + 3][r] = v.w;
        }
        // B tile: 128 "rows" x 16 k
#pragma unroll
        for (int ii = 0; ii < 2; ++ii) {
            int idx = tid + ii * 256;
            int r = idx >> 2, c4 = idx & 3;
            int n = n0 + r;
            const float* wrow;
            if constexpr (MODE == 0) {
                wrow = Wt + (size_t)n * DD;
            } else {
                wrow = (n < GG) ? (Wt + (size_t)n * (2 * DD))
                                : (Wt + (size_t)(n - GG) * (2 * DD) + DD);
            }
            float4 v = *(const float4*)(wrow + kt + c4 * 4);
            Bs[c4 * 4 + 0][r] = v.x;
            Bs[c4 * 4 + 1][r] = v.y;
            Bs[c4 * 4 + 2][r] = v.z;
            Bs[c4 * 4 + 3][r] = v.w;
        }
        __syncthreads();
#pragma unroll
        for (int k = 0; k < 16; ++k) {
            float4 a0 = *(const float4*)&As[k][tm * 8];
            float4 a1 = *(const float4*)&As[k][tm * 8 + 4];
            float4 b0 = *(const float4*)&Bs[k][tn * 4];
            float4 b1 = *(const float4*)&Bs[k][64 + tn * 4];
            float av[8] = {a0.x, a0.y, a0.z, a0.w, a1.x, a1.y, a1.z, a1.w};
            float bv[8] = {b0.x, b0.y, b0.z, b0.w, b1.x, b1.y, b1.z, b1.w};
#pragma unroll
            for (int y = 0; y < 8; ++y)
#pragma unroll
                for (int x = 0; x < 8; ++x) acc[y][x] += av[y] * bv[x];
        }
        __syncthreads();
    }

#pragma unroll
    for (int y = 0; y < 8; ++y) {
        const int m = m0 + tm * 8 + y;
#pragma unroll
        for (int g = 0; g < 2; ++g) {
            int n = n0 + g * 64 + tn * 4;
            float4 v;
            v.x = acc[y][g * 4 + 0];
            v.y = acc[y][g * 4 + 1];
            v.z = acc[y][g * 4 + 2];
            v.w = acc[y][g * 4 + 3];
            float* dst;
            if constexpr (MODE == 0) {
                v.x += bias[n + 0];
                v.y += bias[n + 1];
                v.z += bias[n + 2];
                v.w += bias[n + 3];
                dst = (n < DD) ? (O0 + (size_t)m * DD + n) : (O1 + (size_t)m * DD + (n - DD));
            } else {
                dst = (n < GG) ? (O0 + (size_t)m * GG + n) : (O1 + (size_t)m * GG + (n - GG));
            }
            *(float4*)dst = v;
        }
    }
}

// ---------------------------------------------------------------------------
// candidate score: block-wide q . new_h for pair with a-row ar, b-row br
// ---------------------------------------------------------------------------
__device__ float score_cand(const float* __restrict__ ar, const float* __restrict__ br,
                            const float* __restrict__ cb, const float* __restrict__ cl,
                            const float* __restrict__ cr, const float* __restrict__ q,
                            float* red, int tid) {
    float part = 0.f;
#pragma unroll
    for (int d = tid; d < DD; d += 256) {
        float gi = ar[d] + br[d] + cb[d];
        float gfl = ar[DD + d] + br[DD + d] + cb[DD + d];
        float gfr = ar[2 * DD + d] + br[2 * DD + d] + cb[2 * DD + d];
        float gu = ar[3 * DD + d] + br[3 * DD + d] + cb[3 * DD + d];
        float go = ar[4 * DD + d] + br[4 * DD + d] + cb[4 * DD + d];
        float nc = cl[d] * sigm(gfl + 1.f) + cr[d] * sigm(gfr + 1.f) + tanhf(gu) * sigm(gi);
        float nh = sigm(go) * tanhf(nc);
        part += nh * q[d];
    }
    red[tid] = part;
    __syncthreads();
#pragma unroll
    for (int s = 128; s > 0; s >>= 1) {
        if (tid < s) red[tid] += red[tid + s];
        __syncthreads();
    }
    float r = red[0];
    __syncthreads();
    return r;
}

// ---------------------------------------------------------------------------
// step-0 scores for all 23 candidates per batch (identity seq)
// ---------------------------------------------------------------------------
__global__ __launch_bounds__(256) void scoreall_k(const float* __restrict__ acache,
                                                  const float* __restrict__ bcache,
                                                  const float* __restrict__ cbuf,
                                                  const float* __restrict__ compb,
                                                  const float* __restrict__ q,
                                                  float* __restrict__ scores) {
    __shared__ float red[256];
    const int p = blockIdx.x;
    const int b = blockIdx.y;
    float s = score_cand(acache + (size_t)(b * LL + p) * GG, bcache + (size_t)(b * LL + p + 1) * GG,
                         compb, cbuf + (size_t)(b * LL + p) * DD, cbuf + (size_t)(b * LL + p + 1) * DD,
                         q, red, threadIdx.x);
    if (threadIdx.x == 0) scores[b * NSTEP + p] = s;
}

// ---------------------------------------------------------------------------
// persistent cooperative kernel: all 23 merge steps.
// Per step: phase A (blocks 0..63: reduce partials -> rescore 2 -> argmax ->
// merge h/c, set msel) | grid.sync | phase B (320 tile-tasks on 256 blocks:
// a/b GEMM for the merged row, M=64 N=5120 K=512, KS=4 k-split partials) |
// grid.sync. Per-batch seq/scores state lives in block b's LDS (persistent).
// ---------------------------------------------------------------------------
__global__ __launch_bounds__(256, 2) void loop_k(
    const int* __restrict__ length, float* __restrict__ hbuf, float* __restrict__ cbuf,
    float* __restrict__ acache, float* __restrict__ bcache, float* __restrict__ part,
    const float* __restrict__ scores0, int* __restrict__ msel, const float* __restrict__ comp_W,
    const float* __restrict__ compb, const float* __restrict__ q, float* __restrict__ out) {
    cg::grid_group grid = cg::this_grid();
    __shared__ float As[32][68];  // 68*4=272B rows: 16B-aligned; stride-4 reads -> 2-way (free)
    __shared__ float Bs[32][68];
    __shared__ float red[256];
    __shared__ float sc_l[32];
    __shared__ int seq_l[32];
    __shared__ int k_sh;

    const int tid = threadIdx.x;
    const int bid = blockIdx.x;
    const bool mine = bid < BB;
    const int b = bid;
    int lenb = 0, kp = 0, sml = 0;

    if (mine) {
        lenb = length[b];
        if (tid < NSTEP) sc_l[tid] = scores0[b * NSTEP + tid];
        if (tid < LL) seq_l[tid] = tid;
        __syncthreads();
    }

    for (int i = 0; i < NSTEP; ++i) {
        if (mine) {
            const int ncand = NSTEP - i;
            if (i > 0 && i < lenb) {
                // reduce k-split partials of the merged row into a/b caches
                const int row = b * LL + sml;
                for (int n = tid; n < 2 * GG; n += 256) {
                    float s = 0.f;
#pragma unroll
                    for (int kk = 0; kk < KS; ++kk)
                        s += part[((size_t)(kk * BB + b)) * (2 * GG) + n];
                    if (n < GG) acache[(size_t)row * GG + n] = s;
                    else bcache[(size_t)row * GG + (n - GG)] = s;
                }
                __syncthreads();
                // refresh the (up to) 2 affected candidate scores
                for (int p = kp - 1; p <= kp; ++p) {
                    if (p < 0 || p > ncand - 1) continue;
                    int sl = seq_l[p], sr = seq_l[p + 1];
                    float sc = score_cand(acache + (size_t)(b * LL + sl) * GG,
                                          bcache + (size_t)(b * LL + sr) * GG, compb,
                                          cbuf + (size_t)(b * LL + sl) * DD,
                                          cbuf + (size_t)(b * LL + sr) * DD, q, red, tid);
                    if (tid == 0) sc_l[p] = sc;
                    __syncthreads();
                }
            }
            if (i + 1 < lenb) {
                if (tid == 0) {
                    const int vmax = lenb - i - 2;
                    int k = 0;
                    float best = sc_l[0];
                    for (int p = 1; p <= vmax; ++p)
                        if (sc_l[p] > best) { best = sc_l[p]; k = p; }
                    k_sh = k;
                }
                __syncthreads();
                const int k = k_sh;
                const int sl = seq_l[k], sr = seq_l[k + 1];
                {  // winner gates -> merged h,c into slot sl
                    const float* ar = acache + (size_t)(b * LL + sl) * GG;
                    const float* br = bcache + (size_t)(b * LL + sr) * GG;
                    const float* cl = cbuf + (size_t)(b * LL + sl) * DD;
                    const float* cr = cbuf + (size_t)(b * LL + sr) * DD;
                    float* hw = hbuf + (size_t)(b * LL + sl) * DD;
                    float* cw = cbuf + (size_t)(b * LL + sl) * DD;
#pragma unroll
                    for (int d = tid; d < DD; d += 256) {
                        float gi = ar[d] + br[d] + compb[d];
                        float gfl = ar[DD + d] + br[DD + d] + compb[DD + d];
                        float gfr = ar[2 * DD + d] + br[2 * DD + d] + compb[2 * DD + d];
                        float gu = ar[3 * DD + d] + br[3 * DD + d] + compb[3 * DD + d];
                        float go = ar[4 * DD + d] + br[4 * DD + d] + compb[4 * DD + d];
                        float nc = cl[d] * sigm(gfl + 1.f) + cr[d] * sigm(gfr + 1.f) +
                                   tanhf(gu) * sigm(gi);
                        hw[d] = sigm(go) * tanhf(nc);
                        cw[d] = nc;
                    }
                }
                // shift seq/scores left above k (read-then-write with sync)
                float sv = (tid + 1 < ncand) ? sc_l[tid + 1] : 0.f;
                int qv = (tid + 1 < LL - i) ? seq_l[tid + 1] : 0;
                __syncthreads();
                if (tid >= k + 1 && tid <= ncand - 2) sc_l[tid] = sv;
                if (tid >= k + 1 && tid <= LL - i - 2) seq_l[tid] = qv;
                if (tid == 0) msel[b] = sl;
                kp = k;
                sml = sl;
            }
        }
        grid.sync();
        if (i < NSTEP - 1) {
            // phase B: a/b GEMM partials for row msel[b] of every batch.
            // 320 tasks = 80 n-tiles (NT=64) x KS=4 k-chunks (128 each).
            // Task assignment: all blocks take task=bid; blocks 192..255 take a
            // second task 256+(bid-192) (keeps phase-A blocks 0..63 single-task).
#pragma unroll 1
            for (int pass = 0; pass < 2; ++pass) {
                if (pass == 1 && bid < 192) break;
                const int t = (pass == 0) ? bid : (256 + bid - 192);
                const int kb = t / 80;
                const int ntile = t % 80;
                const int k0 = kb * 128;
                const int tn = tid & 15, tm = tid >> 4;
                float acc[4][4];
#pragma unroll
                for (int y = 0; y < 4; ++y)
#pragma unroll
                    for (int x = 0; x < 4; ++x) acc[y][x] = 0.f;
                for (int kt = 0; kt < 128; kt += 32) {
                    const int kbase = k0 + kt;
#pragma unroll
                    for (int ii = 0; ii < 2; ++ii) {  // A: 64 rows x 32 k
                        int idx = tid + ii * 256;
                        int r = idx >> 3, c4 = idx & 7;
                        const float* arow = hbuf + ((size_t)r * LL + msel[r]) * DD;
                        float4 v = *(const float4*)(arow + kbase + c4 * 4);
                        As[c4 * 4 + 0][r] = v.x;
                        As[c4 * 4 + 1][r] = v.y;
                        As[c4 * 4 + 2][r] = v.z;
                        As[c4 * 4 + 3][r] = v.w;
                    }
#pragma unroll
                    for (int ii = 0; ii < 2; ++ii) {  // B: 64 rows x 32 k
                        int idx = tid + ii * 256;
                        int r = idx >> 3, c4 = idx & 7;
                        int n = ntile * 64 + r;
                        const float* wrow = (n < GG)
                                                ? (comp_W + (size_t)n * (2 * DD))
                                                : (comp_W + (size_t)(n - GG) * (2 * DD) + DD);
                        float4 v = *(const float4*)(wrow + kbase + c4 * 4);
                        Bs[c4 * 4 + 0][r] = v.x;
                        Bs[c4 * 4 + 1][r] = v.y;
                        Bs[c4 * 4 + 2][r] = v.z;
                        Bs[c4 * 4 + 3][r] = v.w;
                    }
                    __syncthreads();
#pragma unroll
                    for (int k = 0; k < 32; ++k) {
                        float4 a = *(const float4*)&As[k][tm * 4];
                        float4 w = *(const float4*)&Bs[k][tn * 4];
                        float av[4] = {a.x, a.y, a.z, a.w};
                        float wv[4] = {w.x, w.y, w.z, w.w};
#pragma unroll
                        for (int y = 0; y < 4; ++y)
#pragma unroll
                            for (int x = 0; x < 4; ++x) acc[y][x] += av[y] * wv[x];
                    }
                    __syncthreads();
                }
#pragma unroll
                for (int y = 0; y < 4; ++y) {
                    int m = tm * 4 + y;
                    float4 v;
                    v.x = acc[y][0];
                    v.y = acc[y][1];
                    v.z = acc[y][2];
                    v.w = acc[y][3];
                    *(float4*)(part + ((size_t)(kb * BB + m)) * (2 * GG) + ntile * 64 + tn * 4) = v;
                }
            }
            grid.sync();
        }
    }

    if (mine) {
        __syncthreads();
        const int s0 = seq_l[0];
        for (int d = tid; d < DD; d += 256) out[b * DD + d] = hbuf[(size_t)(b * LL + s0) * DD + d];
    }
}

// ---------------------------------------------------------------------------
extern "C" void kernel_launch(void* const* d_in, const int* in_sizes, int n_in, void* d_out,
                              int out_size, void* d_ws, size_t ws_size, hipStream_t stream) {
    const float* inp = (const float*)d_in[0];
    const int* length = (const int*)d_in[1];
    const float* word_W = (const float*)d_in[2];
    const float* word_b = (const float*)d_in[3];
    const float* comp_W = (const float*)d_in[4];
    const float* comp_b = (const float*)d_in[5];
    const float* comp_q = (const float*)d_in[6];
    float* out = (float*)d_out;

    float* ws = (float*)d_ws;
    size_t off = 0;
    float* hbuf = ws + off;   off += (size_t)BB * LL * DD;
    float* cbuf = ws + off;   off += (size_t)BB * LL * DD;
    float* acache = ws + off; off += (size_t)BB * LL * GG;
    float* bcache = ws + off; off += (size_t)BB * LL * GG;
    float* part = ws + off;   off += (size_t)KS * BB * 2 * GG;
    float* scores = ws + off; off += 2048;
    int* msel = (int*)(ws + off); off += 64;
    (void)ws_size; (void)in_sizes; (void)n_in; (void)out_size;

    // word projection: h,c = split(inp @ word_W.T + word_b)
    gemm_big<0><<<dim3(8, 12), 256, 0, stream>>>(inp, word_W, word_b, hbuf, cbuf);

    // a/b caches for all 1536 items
    gemm_big<1><<<dim3(40, 12), 256, 0, stream>>>(hbuf, comp_W, nullptr, acache, bcache);

    // step-0 scores
    scoreall_k<<<dim3(23, 64), 256, 0, stream>>>(acache, bcache, cbuf, comp_b, comp_q, scores);

    // all 23 merge steps in one persistent cooperative kernel
    const int* a0 = length;
    float* a1 = hbuf; float* a2 = cbuf; float* a3 = acache; float* a4 = bcache;
    float* a5 = part; const float* a6 = scores; int* a7 = msel;
    const float* a8 = comp_W; const float* a9 = comp_b; const float* a10 = comp_q;
    float* a11 = out;
    void* args[] = {&a0, &a1, &a2, &a3, &a4, &a5, &a6, &a7, &a8, &a9, &a10, &a11};
    hipLaunchCooperativeKernel(reinterpret_cast<void*>(loop_k), dim3(GRID_LOOP), dim3(256),
                               args, 0, stream);
}